// Round 3
// baseline (259.814 us; speedup 1.0000x reference)
//
#include <hip/hip_runtime.h>
#include <math.h>

#define PI_F 3.14159265358979323846f
// swizzles: XOR bank-index bits with higher address bits (bijective, both sides)
#define SWZ16(i) ((i) ^ (((i) >> 4) & 15))  // 4-bit XOR: full odd/even bank spread
#define SWZ8(i)  ((i) ^ (((i) >> 3) & 7))   // used for Wd tile in down-proj phase

// ---------------- Kernel 0: build circular-conv tables from complex spectral weights --
// KK[a][b][c] = (1/S^2) * sum_{u<S, v<=S/2} m_v * ( wr*cos(2pi(ua+vb)/S) - wi*sin(...) )
__global__ __launch_bounds__(256) void build_tables(
    const float* __restrict__ cw_x, const float* __restrict__ cw_z,
    float* __restrict__ KKx, float* __restrict__ KKz)
{
    int tid = blockIdx.x * 256 + threadIdx.x;
    if (tid < 2048) {                    // X branch: S=16, V=9
        int c = tid & 7;
        int ab = tid >> 3;               // a*16+b
        int a = ab >> 4, b = ab & 15;
        float acc = 0.f;
        for (int u = 0; u < 16; ++u) {
            for (int v = 0; v < 9; ++v) {
                float m = (v == 0 || v == 8) ? 1.f : 2.f;
                int ph = (u * a + v * b) & 15;
                float th = (2.f * PI_F / 16.f) * (float)ph;
                float sn, cs;
                sincosf(th, &sn, &cs);
                const float* wp = cw_x + (size_t)((u * 9 + v) * 8 + c) * 2;
                acc += m * (wp[0] * cs - wp[1] * sn);
            }
        }
        KKx[ab * 8 + c] = acc * (1.f / 256.f);
    } else if (tid < 2048 + 512) {       // Z branch: S=8, V=5
        int e = tid - 2048;
        int c = e & 7;
        int ab = e >> 3;                 // a*8+b
        int a = ab >> 3, b = ab & 7;
        float acc = 0.f;
        for (int u = 0; u < 8; ++u) {
            for (int v = 0; v < 5; ++v) {
                float m = (v == 0 || v == 4) ? 1.f : 2.f;
                int ph = (u * a + v * b) & 7;
                float th = (2.f * PI_F / 8.f) * (float)ph;
                float sn, cs;
                sincosf(th, &sn, &cs);
                const float* wp = cw_z + (size_t)((u * 5 + v) * 8 + c) * 2;
                acc += m * (wp[0] * cs - wp[1] * sn);
            }
        }
        KKz[ab * 8 + c] = acc * (1.f / 64.f);
    }
}

// ---------------- Fused kernel: down-proj -> branch -> up-proj, one block per batch ---
// 256 blocks x 320 threads. Block bid owns batch bid: rows [bid*320, bid*320+320).
// Local rows 0..63 = Z tokens, 64..319 = X tokens (matches cat concat order).
// Phase 1: h into LDS (16-lane groups, 4 rows/group/pass, 4 passes).
// Phase 2: LN1 -> circular conv (swizzled LDS) -> LN2 -> MLP -> catS in LDS.
// Phase 3: up-proj; wave owns 64 rows, lane owns 3 f4-columns -> 1KB coalesced stores.
__global__ __launch_bounds__(320) void fused_kernel(
    const float* __restrict__ x, const float* __restrict__ Wd,
    const float* __restrict__ bd,
    const float* __restrict__ KKx, const float* __restrict__ KKz,
    const float* __restrict__ g1v, const float* __restrict__ b1v,
    const float* __restrict__ g2v, const float* __restrict__ b2v,
    const float* __restrict__ W1, const float* __restrict__ b1m,
    const float* __restrict__ W2, const float* __restrict__ b2m,
    const float* __restrict__ Wu, const float* __restrict__ bu,
    float* __restrict__ out)
{
    __shared__ float4 wds[1536];      // 24KB  Wd swizzled
    __shared__ float  hSf[320 * 9];   // 11.25KB  h rows, stride 9 (conflict-free)
    __shared__ float4 kkx[512];       // 8KB   X conv table
    __shared__ float4 kkz[128];       // 2KB   Z conv table
    __shared__ float4 t1x[512];       // 8KB   X t1 tile (swizzled)
    __shared__ float4 t1z[128];       // 2KB   Z t1 tile (swizzled)
    __shared__ float  catS[320 * 9];  // 11.25KB cat rows, stride 9
    __shared__ float  sW1[128], sW2[128], sB1[16], sB2[8];
    __shared__ float  sG1[8], sH1[8], sG2[8], sH2[8];

    int t = threadIdx.x;
    int bid = blockIdx.x;

    // ---- stage Wd, tables, params ----
    const float4* Wd4 = (const float4*)Wd;
    for (int i = t; i < 1536; i += 320) wds[SWZ8(i)] = Wd4[i];
    for (int i = t; i < 512; i += 320) kkx[i] = ((const float4*)KKx)[i];
    if (t < 128) kkz[t] = ((const float4*)KKz)[t];
    if (t < 128) { sW1[t] = W1[t]; sW2[t] = W2[t]; }
    if (t < 16)  sB1[t] = b1m[t];
    if (t < 8) { sB2[t] = b2m[t]; sG1[t] = g1v[t]; sH1[t] = b1v[t]; sG2[t] = g2v[t]; sH2[t] = b2v[t]; }
    float bdv[8];
    #pragma unroll
    for (int c = 0; c < 8; ++c) bdv[c] = bd[c];
    __syncthreads();

    // ---- phase 1: h = x @ Wd + bd for this block's 320 rows, into hSf ----
    {
        int g = t >> 4;                  // 20 groups of 16 lanes
        int l = t & 15;
        const float4* x4 = (const float4*)x;
        for (int p = 0; p < 4; ++p) {
            int lr0 = g * 16 + p * 4;    // local rows lr0..lr0+3
            const float4* xr = x4 + ((size_t)bid * 320 + lr0) * 192;
            float acc[4][8];
            #pragma unroll
            for (int r = 0; r < 4; ++r)
                #pragma unroll
                for (int c = 0; c < 8; ++c) acc[r][c] = 0.f;
            #pragma unroll
            for (int j = 0; j < 12; ++j) {
                float4 v[4];
                #pragma unroll
                for (int r = 0; r < 4; ++r) v[r] = xr[(size_t)r * 192 + l + 16 * j];
                #pragma unroll
                for (int e = 0; e < 4; ++e) {
                    int f4i = ((l + 16 * j) * 4 + e) * 2;        // even
                    int sw = SWZ8(f4i);
                    float4 w0 = wds[sw];
                    float4 w1 = wds[sw ^ 1];                     // SWZ8(f4i+1)==SWZ8(f4i)^1
                    #pragma unroll
                    for (int r = 0; r < 4; ++r) {
                        float xv = (e == 0) ? v[r].x : (e == 1) ? v[r].y : (e == 2) ? v[r].z : v[r].w;
                        acc[r][0] += xv * w0.x;  acc[r][1] += xv * w0.y;
                        acc[r][2] += xv * w0.z;  acc[r][3] += xv * w0.w;
                        acc[r][4] += xv * w1.x;  acc[r][5] += xv * w1.y;
                        acc[r][6] += xv * w1.z;  acc[r][7] += xv * w1.w;
                    }
                }
            }
            #pragma unroll
            for (int off = 1; off < 16; off <<= 1)
                #pragma unroll
                for (int r = 0; r < 4; ++r)
                    #pragma unroll
                    for (int c = 0; c < 8; ++c)
                        acc[r][c] += __shfl_xor(acc[r][c], off, 64);
            if (l < 4) {
                float o[8];
                #pragma unroll
                for (int c = 0; c < 8; ++c)
                    o[c] = (l == 0) ? acc[0][c] : (l == 1) ? acc[1][c] : (l == 2) ? acc[2][c] : acc[3][c];
                int lr = lr0 + l;
                #pragma unroll
                for (int c = 0; c < 8; ++c) hSf[lr * 9 + c] = o[c] + bdv[c];
            }
        }
    }
    __syncthreads();

    // ---- phase 2: LN1 -> conv -> LN2 -> MLP -> catS ----
    bool isX = (t < 256);
    int lr = isX ? (64 + t) : (t - 256);
    float raw[8];
    #pragma unroll
    for (int c = 0; c < 8; ++c) raw[c] = hSf[lr * 9 + c];

    float mean = 0.f;
    #pragma unroll
    for (int c = 0; c < 8; ++c) mean += raw[c];
    mean *= 0.125f;
    float var = 0.f;
    #pragma unroll
    for (int c = 0; c < 8; ++c) { float d = raw[c] - mean; var += d * d; }
    var *= 0.125f;
    float inv = rsqrtf(var + 1e-5f);
    float t1[8];
    #pragma unroll
    for (int c = 0; c < 8; ++c) t1[c] = (raw[c] - mean) * inv * sG1[c] + sH1[c];

    if (isX) {
        int i0 = 2 * t;
        t1x[SWZ16(i0)]     = make_float4(t1[0], t1[1], t1[2], t1[3]);
        t1x[SWZ16(i0 + 1)] = make_float4(t1[4], t1[5], t1[6], t1[7]);
    } else {
        int tz = t - 256;
        int i0 = 2 * tz;
        t1z[SWZ16(i0)]     = make_float4(t1[0], t1[1], t1[2], t1[3]);
        t1z[SWZ16(i0 + 1)] = make_float4(t1[4], t1[5], t1[6], t1[7]);
    }
    __syncthreads();

    float s0=0.f,s1=0.f,s2=0.f,s3=0.f,s4=0.f,s5=0.f,s6=0.f,s7=0.f;
    if (isX) {
        int p = t >> 4, q = t & 15;
        for (int da = 0; da < 16; ++da) {
            int qp = (q - da) & 15;
            #pragma unroll
            for (int db = 0; db < 16; ++db) {
                int pp = (p - db) & 15;
                int si = (pp * 16 + qp) * 2;            // even
                int sw = SWZ16(si);
                float4 v0 = t1x[sw];
                float4 v1 = t1x[sw ^ 1];                // SWZ16(si+1)==SWZ16(si)^1
                int kb = (da * 16 + db) * 2;
                float4 k0 = kkx[kb], k1 = kkx[kb + 1];  // uniform addr -> broadcast
                s0 += k0.x * v0.x;  s1 += k0.y * v0.y;
                s2 += k0.z * v0.z;  s3 += k0.w * v0.w;
                s4 += k1.x * v1.x;  s5 += k1.y * v1.y;
                s6 += k1.z * v1.z;  s7 += k1.w * v1.w;
            }
        }
    } else {
        int tz = t - 256;
        int p = tz >> 3, q = tz & 7;
        for (int da = 0; da < 8; ++da) {
            int qp = (q - da) & 7;
            #pragma unroll
            for (int db = 0; db < 8; ++db) {
                int pp = (p - db) & 7;
                int si = (pp * 8 + qp) * 2;             // even
                int sw = SWZ16(si);
                float4 v0 = t1z[sw];
                float4 v1 = t1z[sw ^ 1];
                int kb = (da * 8 + db) * 2;
                float4 k0 = kkz[kb], k1 = kkz[kb + 1];
                s0 += k0.x * v0.x;  s1 += k0.y * v0.y;
                s2 += k0.z * v0.z;  s3 += k0.w * v0.w;
                s4 += k1.x * v1.x;  s5 += k1.y * v1.y;
                s6 += k1.z * v1.z;  s7 += k1.w * v1.w;
            }
        }
    }

    float sarr[8] = {s0, s1, s2, s3, s4, s5, s6, s7};
    float m2 = 0.f;
    #pragma unroll
    for (int c = 0; c < 8; ++c) m2 += sarr[c];
    m2 *= 0.125f;
    float v2 = 0.f;
    #pragma unroll
    for (int c = 0; c < 8; ++c) { float d = sarr[c] - m2; v2 += d * d; }
    v2 *= 0.125f;
    float inv2 = rsqrtf(v2 + 1e-5f);
    float t2[8];
    #pragma unroll
    for (int c = 0; c < 8; ++c) t2[c] = (sarr[c] - m2) * inv2 * sG2[c] + sH2[c];

    float hm[16];
    #pragma unroll
    for (int j = 0; j < 16; ++j) {
        float acc = sB1[j];
        #pragma unroll
        for (int c = 0; c < 8; ++c) acc += t2[c] * sW1[c * 16 + j];
        hm[j] = 0.5f * acc * (1.f + erff(acc * 0.70710678118654752f));  // exact GELU
    }
    #pragma unroll
    for (int c = 0; c < 8; ++c) {
        float acc = sB2[c];
        #pragma unroll
        for (int j = 0; j < 16; ++j) acc += hm[j] * sW2[j * 8 + c];
        catS[lr * 9 + c] = acc + raw[c];
    }
    __syncthreads();

    // ---- phase 3: out = cat @ Wu + bu ; wave owns 64 rows, lane owns 3 f4-cols ----
    {
        int wv = t >> 6;                 // 0..4
        int ln = t & 63;
        const float4* Wu4 = (const float4*)Wu;
        float4 wr[24];                   // [c*3+k]
        #pragma unroll
        for (int c = 0; c < 8; ++c)
            #pragma unroll
            for (int k = 0; k < 3; ++k)
                wr[c * 3 + k] = Wu4[c * 192 + ln + 64 * k];
        float4 bv[3];
        #pragma unroll
        for (int k = 0; k < 3; ++k) bv[k] = ((const float4*)bu)[ln + 64 * k];

        for (int r = 0; r < 64; ++r) {
            int lrow = wv * 64 + r;
            float cv[8];
            #pragma unroll
            for (int c = 0; c < 8; ++c) cv[c] = catS[lrow * 9 + c];  // broadcast
            float4* o4 = (float4*)out + ((size_t)bid * 320 + lrow) * 192 + ln;
            #pragma unroll
            for (int k = 0; k < 3; ++k) {
                float4 a = bv[k];
                #pragma unroll
                for (int c = 0; c < 8; ++c) {
                    a.x += cv[c] * wr[c * 3 + k].x;
                    a.y += cv[c] * wr[c * 3 + k].y;
                    a.z += cv[c] * wr[c * 3 + k].z;
                    a.w += cv[c] * wr[c * 3 + k].w;
                }
                o4[64 * k] = a;          // 64 lanes x 16B = 1KB contiguous
            }
        }
    }
}

extern "C" void kernel_launch(void* const* d_in, const int* in_sizes, int n_in,
                              void* d_out, int out_size, void* d_ws, size_t ws_size,
                              hipStream_t stream)
{
    (void)in_sizes; (void)n_in; (void)out_size; (void)ws_size;
    const float* x    = (const float*)d_in[0];
    const float* Wd   = (const float*)d_in[1];
    const float* bd   = (const float*)d_in[2];
    const float* cw_x = (const float*)d_in[3];
    const float* cw_z = (const float*)d_in[4];
    const float* g1   = (const float*)d_in[5];
    const float* h1   = (const float*)d_in[6];
    const float* g2   = (const float*)d_in[7];
    const float* h2   = (const float*)d_in[8];
    const float* W1   = (const float*)d_in[9];
    const float* b1   = (const float*)d_in[10];
    const float* W2   = (const float*)d_in[11];
    const float* b2   = (const float*)d_in[12];
    const float* Wu   = (const float*)d_in[13];
    const float* bu   = (const float*)d_in[14];
    float* out = (float*)d_out;

    float* KKx = (float*)d_ws;          // 2048 floats
    float* KKz = KKx + 2048;            // 512 floats

    hipLaunchKernelGGL(build_tables, dim3(10), dim3(256), 0, stream, cw_x, cw_z, KKx, KKz);
    hipLaunchKernelGGL(fused_kernel, dim3(256), dim3(320), 0, stream,
                       x, Wd, bd, KKx, KKz, g1, h1, g2, h2,
                       W1, b1, W2, b2, Wu, bu, out);
}